// Round 7
// baseline (158.411 us; speedup 1.0000x reference)
//
#include <hip/hip_runtime.h>
#include <hip/hip_bf16.h>

// VQ-VAE vector quantizer, MI355X gfx950 — round 7 (R6 design, stride bugfix).
// prep:     W fp32 -> bf16 PRE-PERMUTED into MFMA-fragment order (tile = 16
//           codes = 4096 shorts), + ||w||^2, + zero accumulators.
// vq_fused: 512 blocks x 256 thr (2 blocks/CU). Per wave: 64 rows x its own
//           256 codes (ksplit-4). Phase A: coalesced z read + LDS transpose.
//           K-loop: per-wave independent dbuf via global_load_lds, vmcnt(8)
//           gating, NO barriers. Merge, gather W rows via DMA into dead B-buf,
//           transposed coalesced z_q write, loss = sum z^2 + best_dist.

#define DIM      256
#define SPB      1024
#define ZQ_ELEMS 8388608
#define NBLK     512
#define TILE_SH  4096      // shorts per 16-code tile (16 x 256)

// LDS map (bytes)
#define LDS_ZS    65536    // zs: 64 rows x 36 f32 (9216 B)
#define LDS_WNL   74752    // 1024 f32
#define LDS_MD    78848    // 4 x 64 f32
#define LDS_MI    79872    // 4 x 64 int
#define LDS_RIDX  80896    // 64 int
#define LDS_Z2    81152    // 4 f32
#define LDS_SIZE  81168

typedef float f32x4  __attribute__((ext_vector_type(4)));
typedef short bf16x8 __attribute__((ext_vector_type(8)));

__device__ __forceinline__ short f2bf(float f) {
    union { float f; unsigned u; } v; v.f = f;
    unsigned r = v.u + 0x7FFFu + ((v.u >> 16) & 1u);   // RNE
    return (short)(r >> 16);
}

#define GLL16(g, l)                                                            \
    __builtin_amdgcn_global_load_lds(                                          \
        (const __attribute__((address_space(1))) void*)(g),                    \
        (__attribute__((address_space(3))) void*)(l), 16, 0, 0)

// ---------------- K1: prep ----------------
// wbf layout: tile kt (16 codes) = TILE_SH shorts; granule G = T*64 + q*16 + c16
// holds w[kt*16+c16][32T+8q .. +7] as bf16x8. Grid 128 x 256.
__global__ __launch_bounds__(256) void prep(const float* __restrict__ w,
                                            short* __restrict__ wbf,
                                            float* __restrict__ wn,
                                            float* __restrict__ acc,
                                            unsigned* __restrict__ done) {
    const int g = blockIdx.x * 256 + threadIdx.x;   // 0..32767
    const int k = g >> 5, T = (g >> 2) & 7, q = g & 3;
    const float* src = w + (size_t)k * DIM + 32 * T + 8 * q;
    f32x4 v0 = *(const f32x4*)src;
    f32x4 v1 = *(const f32x4*)(src + 4);
    bf16x8 p;
    p[0]=f2bf(v0[0]); p[1]=f2bf(v0[1]); p[2]=f2bf(v0[2]); p[3]=f2bf(v0[3]);
    p[4]=f2bf(v1[0]); p[5]=f2bf(v1[1]); p[6]=f2bf(v1[2]); p[7]=f2bf(v1[3]);
    *(bf16x8*)(wbf + (size_t)(k >> 4) * TILE_SH
                   + (T * 64 + q * 16 + (k & 15)) * 8) = p;
    float s = v0[0]*v0[0]+v0[1]*v0[1]+v0[2]*v0[2]+v0[3]*v0[3]
            + v1[0]*v1[0]+v1[1]*v1[1]+v1[2]*v1[2]+v1[3]*v1[3];
#pragma unroll
    for (int m = 1; m <= 16; m <<= 1) s += __shfl_xor(s, m);   // 32-lane groups
    if ((threadIdx.x & 31) == 0) wn[k] = s;
    if (g == 0) { *acc = 0.f; *done = 0u; }
}

// ---------------- K2: fused main ----------------
__global__ __launch_bounds__(256, 2) void vq_fused(const float* __restrict__ z,
                                                   const float* __restrict__ w,
                                                   const short* __restrict__ wbf,
                                                   const float* __restrict__ wn,
                                                   float* __restrict__ out,
                                                   float* __restrict__ acc,
                                                   unsigned* __restrict__ done) {
    __shared__ __align__(16) char smem[LDS_SIZE];
    float* zs   = (float*)(smem + LDS_ZS);
    float* wnl  = (float*)(smem + LDS_WNL);
    float* md   = (float*)(smem + LDS_MD);
    int*   mi   = (int*)(smem + LDS_MI);
    int*   ridx = (int*)(smem + LDS_RIDX);
    float* z2w  = (float*)(smem + LDS_Z2);

    const int t = threadIdx.x, wv = t >> 6, l = t & 63;
    const int n16 = l & 15, q = l >> 4;
    const int n0 = blockIdx.x * 64, batch = n0 >> 10, sbase = n0 & 1023;
    const float* zb = z + (size_t)batch * (DIM * SPB) + sbase;
    const short* wtile = wbf + (size_t)wv * 16 * TILE_SH;  // this wave's tiles
    char* buf0 = smem + wv * 16384;
    char* buf1 = buf0 + 8192;

    // kick B tiles 0,1 (async DMA; contiguous 1KB per instr)
#pragma unroll
    for (int i = 0; i < 8; ++i)
        GLL16(wtile + i * 512 + l * 8, buf0 + i * 1024 + l * 16);
#pragma unroll
    for (int i = 0; i < 8; ++i)
        GLL16(wtile + TILE_SH + i * 512 + l * 8, buf1 + i * 1024 + l * 16);

    // wnorm -> LDS (each wave writes its own 256-code slice)
    { f32x4 v = *(const f32x4*)(wn + 4 * t); *(f32x4*)(wnl + 4 * t) = v; }

    // ---- Phase A: coalesced z read + LDS transpose -> af regs, 8 rounds ----
    const int cg2 = t >> 4, sx = t & 15;
    f32x4 pv[2][2];
#pragma unroll
    for (int r = 0; r < 2; ++r)
#pragma unroll
        for (int u = 0; u < 2; ++u)
            pv[r][u] = *(const f32x4*)(zb + (size_t)(r * 32 + 2 * cg2 + u) * SPB + 4 * sx);

    bf16x8 af[4][8];
    float z2t = 0.f;
#pragma unroll 1
    for (int cc = 0; cc < 8; ++cc) {
        f32x4 a0 = pv[cc & 1][0], a1 = pv[cc & 1][1];
        z2t += a0[0]*a0[0]+a0[1]*a0[1]+a0[2]*a0[2]+a0[3]*a0[3];
        z2t += a1[0]*a1[0]+a1[1]*a1[1]+a1[2]*a1[2]+a1[3]*a1[3];
        __syncthreads();                       // prev round's zs reads done
#pragma unroll
        for (int e = 0; e < 4; ++e) {
            zs[(4 * sx + e) * 36 + 2 * cg2]     = a0[e];
            zs[(4 * sx + e) * 36 + 2 * cg2 + 1] = a1[e];
        }
        if (cc < 6) {
#pragma unroll
            for (int u = 0; u < 2; ++u)
                pv[cc & 1][u] = *(const f32x4*)(zb + (size_t)((cc + 2) * 32 + 2 * cg2 + u) * SPB + 4 * sx);
        }
        __syncthreads();
#pragma unroll
        for (int set = 0; set < 4; ++set) {    // rows 16set+n16, d = 32cc+8q+j
            const float* zr = &zs[(16 * set + n16) * 36 + 8 * q];
            f32x4 e0 = *(const f32x4*)zr;
            f32x4 e1 = *(const f32x4*)(zr + 4);
            bf16x8 a;
            a[0]=f2bf(e0[0]); a[1]=f2bf(e0[1]); a[2]=f2bf(e0[2]); a[3]=f2bf(e0[3]);
            a[4]=f2bf(e1[0]); a[5]=f2bf(e1[1]); a[6]=f2bf(e1[2]); a[7]=f2bf(e1[3]);
            af[set][cc] = a;
        }
    }

    // ---- K-loop: per-wave independent, no barriers ----
    float best[4][4];
    int   bidx[4][4];
#pragma unroll
    for (int s = 0; s < 4; ++s)
#pragma unroll
        for (int r = 0; r < 4; ++r) { best[s][r] = 3.4e38f; bidx[s][r] = 0; }

#pragma unroll 2
    for (int kt = 0; kt < 16; ++kt) {
        const char* rb = (kt & 1) ? buf1 : buf0;
        __builtin_amdgcn_s_waitcnt(0x0F78);    // vmcnt(8): current tile resident
        f32x4 ac[4];
#pragma unroll
        for (int s = 0; s < 4; ++s) ac[s] = (f32x4){0.f, 0.f, 0.f, 0.f};
#pragma unroll
        for (int T = 0; T < 8; ++T) {
            bf16x8 b = *(const bf16x8*)(rb + T * 1024 + l * 16);   // stride-1
#pragma unroll
            for (int s = 0; s < 4; ++s)
                ac[s] = __builtin_amdgcn_mfma_f32_16x16x32_bf16(af[s][T], b, ac[s], 0, 0, 0);
        }
        if (kt < 15) {                          // prefetch kt+2 into current buf
            const int st = (kt + 2 < 16) ? (kt + 2) : 15;   // kt=14: junk reload
            const short* tn = wtile + (size_t)st * TILE_SH;
            char* db = (kt & 1) ? buf1 : buf0;
#pragma unroll
            for (int i = 0; i < 8; ++i)
                GLL16(tn + i * 512 + l * 8, db + i * 1024 + l * 16);
        }
        const int   k0  = (wv << 8) + (kt << 4) + n16;
        const float wnv = wnl[k0];
#pragma unroll
        for (int s = 0; s < 4; ++s)
#pragma unroll
            for (int r = 0; r < 4; ++r) {
                float d = wnv - 2.f * ac[s][r];
                if (d < best[s][r]) { best[s][r] = d; bidx[s][r] = k0; }
            }
    }

    // intra-wave argmin over the 16 code lanes (low-index tie-break)
#pragma unroll
    for (int s = 0; s < 4; ++s)
#pragma unroll
        for (int r = 0; r < 4; ++r) {
            float bv = best[s][r];
            int   bi = bidx[s][r];
#pragma unroll
            for (int m = 1; m < 16; m <<= 1) {
                float ov = __shfl_xor(bv, m);
                int   oi = __shfl_xor(bi, m);
                if (ov < bv || (ov == bv && oi < bi)) { bv = ov; bi = oi; }
            }
            if (n16 == 0) {
                int row = 16 * s + 4 * q + r;
                md[wv * 64 + row] = bv;
                mi[wv * 64 + row] = bi;
            }
        }

    // z2 wave reduce
#pragma unroll
    for (int off = 32; off; off >>= 1) z2t += __shfl_down(z2t, off);
    if (l == 0) z2w[wv] = z2t;

    __syncthreads();

    // merge 4 ksplit parts (ascending wv = ascending code range -> tie ok)
    float lsum = 0.f;
    if (t < 64) {
        float dm = md[t];
        int   km = mi[t];
#pragma unroll
        for (int h = 1; h < 4; ++h) {
            float dh = md[h * 64 + t];
            int   kh = mi[h * 64 + t];
            if (dh < dm) { dm = dh; km = kh; }
        }
        ridx[t] = km;
        lsum = dm;
        if (t == 0) lsum += z2w[0] + z2w[1] + z2w[2] + z2w[3];
    }
    __syncthreads();

    // drain any in-flight junk prefetch before gather DMA reuses B-buf LDS
    __builtin_amdgcn_s_waitcnt(0x0F70);        // vmcnt(0)

    // gather selected W rows (fp32), rotated by s granules; each wave's dst is
    // its OWN dead B-buf region -> per-wave DMA FIFO ordering suffices.
#pragma unroll 1
    for (int s2 = 0; s2 < 16; ++s2) {
        int s  = 16 * wv + s2;
        int ks = ridx[s];
        GLL16(w + (size_t)ks * DIM + 4 * ((l - s) & 63),
              smem + s * 1024 + l * 16);
    }
    __builtin_amdgcn_s_waitcnt(0x0F70);        // vmcnt(0)
    __syncthreads();

    // transposed, coalesced z_q write: w_row[s][c] at phys dword (c+4s)&255
    float* zql = (float*)smem;
    float* ob  = out + (size_t)batch * (DIM * SPB) + sbase;
    const int x = t & 15, cg = t >> 4;
#pragma unroll 2
    for (int i = 0; i < 16; ++i) {
        int c = cg + 16 * i;
        f32x4 qv;
#pragma unroll
        for (int r = 0; r < 4; ++r) {
            int s = 4 * x + r;
            qv[r] = zql[s * 256 + ((c + 4 * s) & 255)];
        }
        *(f32x4*)(ob + (size_t)c * SPB + 4 * x) = qv;
    }

    // loss: sum z^2 + sum best_dist, one atomic per block; last block finalizes
    if (wv == 0) {
#pragma unroll
        for (int off = 32; off; off >>= 1) lsum += __shfl_down(lsum, off);
        if (t == 0) {
            atomicAdd(acc, lsum);
            __threadfence();
            unsigned prev = atomicAdd(done, 1u);
            if (prev == NBLK - 1) {
                float v = atomicAdd(acc, 0.f) * (1.f / 8388608.f);
                out[ZQ_ELEMS]     = v;
                out[ZQ_ELEMS + 1] = v;
            }
        }
    }
}

extern "C" void kernel_launch(void* const* d_in, const int* in_sizes, int n_in,
                              void* d_out, int out_size, void* d_ws, size_t ws_size,
                              hipStream_t stream) {
    const float* z = (const float*)d_in[0];
    const float* w = (const float*)d_in[1];
    float* out = (float*)d_out;

    char* ws = (char*)d_ws;
    short*    wbf  = (short*)ws;                   // 64 tiles x 4096 sh = 512 KB
    float*    wn   = (float*)(ws + 524288);        // 4 KB
    float*    acc  = (float*)(ws + 528384);
    unsigned* done = (unsigned*)(ws + 528388);

    prep<<<128, 256, 0, stream>>>(w, wbf, wn, acc, done);
    vq_fused<<<NBLK, 256, 0, stream>>>(z, w, wbf, wn, out, acc, done);
}